// Round 10
// baseline (170.373 us; speedup 1.0000x reference)
//
#include <hip/hip_runtime.h>
#include <stdint.h>

#define E 8192
#define KACT 164           // ceil(0.02 * 8192)
#define TPR 256            // threads per row
#define RPB 4              // rows per block
#define TPB (TPR * RPB)    // 1024

typedef float floatx4 __attribute__((ext_vector_type(4)));  // NT-store-compatible

__device__ __forceinline__ unsigned int keyxform(unsigned int s) {
    return (s & 0x80000000u) ? ~s : (s | 0x80000000u);
}

// ---------------- ws layout: [0]=max bits (uint, >=0 float), [1]=winner count
__global__ void init_ws_kernel(unsigned int* ws) {
    ws[0] = 0u;
    ws[1] = 0u;
}

// ---------------- global max(0, max(tensor)) -> ws[0] as uint bits
__global__ void __launch_bounds__(256) gmax_kernel(const float* __restrict__ T,
                                                   unsigned int* __restrict__ ws,
                                                   int n4) {
    __shared__ float wmax[4];
    int tid = blockIdx.x * 256 + threadIdx.x;
    int stride = gridDim.x * 256;
    const float4* T4 = (const float4*)T;
    float m = 0.0f;  // clamp at 0 built in
    for (int i = tid; i < n4; i += stride) {
        float4 v = T4[i];
        m = fmaxf(m, fmaxf(fmaxf(v.x, v.y), fmaxf(v.z, v.w)));
    }
    for (int d = 32; d >= 1; d >>= 1) m = fmaxf(m, __shfl_xor(m, d, 64));
    int lane = threadIdx.x & 63, wid = threadIdx.x >> 6;
    if (lane == 0) wmax[wid] = m;
    __syncthreads();
    if (threadIdx.x == 0) {
        m = fmaxf(fmaxf(wmax[0], wmax[1]), fmaxf(wmax[2], wmax[3]));
        atomicMax(ws, __float_as_uint(m));
    }
}

// ---------------- per-row top-k select + outputs, 4 rows per 1024-thread block
// 16 waves/block at VGPR~64 -> up to 2 blocks (32 waves) per CU for latency
// hiding. Keys register-resident; statistical pivot (mu + a*sigma) with exact
// count check + fallback ladder prunes the histogram to ~400 candidates/row
// (exact for any data: candidate set provably contains the k-th key when
// count >= KACT, else the pivot relaxes down the ladder to 0 = full set).
template <int MODE>
__global__ void __launch_bounds__(TPB, 4) select_kernel(
    const float* __restrict__ T, const float* __restrict__ BT,
    const float* __restrict__ BP, const unsigned int* __restrict__ ws_max,
    float* __restrict__ out, float* __restrict__ boost_out,
    unsigned int* __restrict__ count, int Btot) {

    __shared__ unsigned int hist[4][RPB][256];  // one buffer per radix level
    __shared__ float sred[RPB][4][2];           // per-wave sum, sumsq
    __shared__ unsigned int scw[RPB][4][2];     // per-wave candidate counts
    __shared__ unsigned int s_tot[RPB], s_fkk[RPB];
    __shared__ unsigned int cntJW[RPB][8][4];
    __shared__ unsigned int scnt;

    if (MODE == 1) {
        if (count[0] != 0u) return;  // uniform: fallback not needed
    }

    const int t = threadIdx.x;
    const int r = t >> 8;           // row within block (0..3)
    const int tr = t & (TPR - 1);   // thread within row
    const int lane = t & 63;
    const int wrow = (t >> 6) & 3;  // wave within row group
    int row = blockIdx.x * RPB + r;
    const bool rowValid = (row < Btot);
    if (!rowValid) row = Btot - 1;  // safe addresses; stores predicated
    const size_t base = (size_t)row * E;

    if (t == 0) scnt = 0u;
    // zero all 4 hist buffers once (4*4*256 = 4096 uints = 1024 uint4, 1024 thr)
    {
        uint4 z = {0u, 0u, 0u, 0u};
        ((uint4*)hist)[t] = z;
    }

    const float c = __uint_as_float(ws_max[0]) * BP[0];

    const float4* T4 = (const float4*)(T + base);
    const float4* BT4 = (const float4*)(BT + base);

    unsigned int keys[32];
    unsigned int m_sg = 0u;  // x>0 bitmask over 32 owned elements
    float bsum = 0.0f, bsq = 0.0f;

    // ---- load pass: keys to registers + running stats (pure read)
#pragma unroll
    for (int j = 0; j < 8; ++j) {
        int u = j * TPR + tr;
        float4 tv = T4[u];
        float4 bv = BT4[u];
        float xs[4] = {tv.x, tv.y, tv.z, tv.w};
        float bs[4] = {bv.x, bv.y, bv.z, bv.w};
#pragma unroll
        for (int i = 0; i < 4; ++i) {
            float b = bs[i] + c;
            float x = xs[i];
            float boosted = (x > 0.0f ? x : 0.0f) + b;
            keys[j * 4 + i] = keyxform(__float_as_uint(boosted));
            if (x > 0.0f) m_sg |= (1u << (j * 4 + i));
            bsum += boosted;
            bsq += boosted * boosted;
        }
    }

    // ---- per-row mean/sigma (register + shfl reduce, 1 barrier)
#pragma unroll
    for (int d = 32; d >= 1; d >>= 1) {
        bsum += __shfl_xor(bsum, d, 64);
        bsq += __shfl_xor(bsq, d, 64);
    }
    if (lane == 0) { sred[r][wrow][0] = bsum; sred[r][wrow][1] = bsq; }
    __syncthreads();  // also covers hist zeroing + scnt
    float S = 0.0f, Q = 0.0f;
#pragma unroll
    for (int w = 0; w < 4; ++w) { S += sred[r][w][0]; Q += sred[r][w][1]; }
    const float mu = S * (1.0f / E);
    const float sig = sqrtf(fmaxf(Q * (1.0f / E) - mu * mu, 0.0f));
    const unsigned int V1k = keyxform(__float_as_uint(mu + 2.2f * sig));
    const unsigned int V2k = keyxform(__float_as_uint(mu + 0.8f * sig));

    // ---- exact candidate counts for both pivots (register compares)
    unsigned int c1 = 0u, c2 = 0u;
#pragma unroll
    for (int s2 = 0; s2 < 32; ++s2) {
        c1 += (keys[s2] > V1k) ? 1u : 0u;
        c2 += (keys[s2] > V2k) ? 1u : 0u;
    }
#pragma unroll
    for (int d = 32; d >= 1; d >>= 1) {
        c1 += __shfl_xor(c1, d, 64);
        c2 += __shfl_xor(c2, d, 64);
    }
    if (lane == 0) { scw[r][wrow][0] = c1; scw[r][wrow][1] = c2; }
    __syncthreads();
    unsigned int n1 = 0u, n2 = 0u;
#pragma unroll
    for (int w = 0; w < 4; ++w) { n1 += scw[r][w][0]; n2 += scw[r][w][1]; }
    // pivot ladder: V1 if enough candidates, else V2, else full (exact)
    const unsigned int pivKey =
        (n1 >= KACT) ? V1k : ((n2 >= KACT) ? V2k : 0u);

    // ---- radix select among candidates: 4 x 8-bit levels, exact
    unsigned int prefix = 0u;
    unsigned int kk = KACT;
    unsigned int totEq = 0u;
#pragma unroll
    for (int level = 0; level < 4; ++level) {
        const int shift = 24 - 8 * level;
        unsigned int* H = &hist[level][r][0];
#pragma unroll
        for (int s2 = 0; s2 < 32; ++s2) {
            unsigned int key = keys[s2];
            bool match = (key > pivKey) &&
                         ((level == 0) || ((key >> (shift + 8)) == prefix));
            if (match) atomicAdd(&H[(key >> shift) & 255u], 1u);
        }
        __syncthreads();  // single barrier per level (buffers pre-zeroed)

        // wave-autonomous suffix scan: lane reads bins 4*lane .. 4*lane+3
        const uint4* H4 = (const uint4*)H;
        uint4 h4 = H4[lane];
        unsigned int sf3 = h4.w;
        unsigned int sf2 = h4.z + sf3;
        unsigned int sf1 = h4.y + sf2;
        unsigned int sf0 = h4.x + sf1;  // suffix within quad (incl.)
        unsigned int v = sf0;           // quad total
#pragma unroll
        for (int d = 1; d < 64; d <<= 1) {
            unsigned int x = __shfl_down(v, d, 64);
            if (lane + d < 64) v += x;
        }
        unsigned int exclAbove = v - sf0;  // sum of quads in lanes > lane
        unsigned int S0 = sf0 + exclAbove, S1 = sf1 + exclAbove;
        unsigned int S2 = sf2 + exclAbove, S3 = sf3 + exclAbove;
        // unique bin where cumulative (from top) crosses kk
        int hi = -1;
        unsigned int hS = 0u, hH = 0u;
        if (S3 >= kk && S3 - h4.w < kk) { hi = 3; hS = S3; hH = h4.w; }
        if (S2 >= kk && S2 - h4.z < kk) { hi = 2; hS = S2; hH = h4.z; }
        if (S1 >= kk && S1 - h4.y < kk) { hi = 1; hS = S1; hH = h4.y; }
        if (S0 >= kk && S0 - h4.x < kk) { hi = 0; hS = S0; hH = h4.x; }
        unsigned long long bal = __ballot(hi >= 0);
        int src = __ffsll((long long)bal) - 1;
        unsigned int binL = (unsigned int)(4 * lane + hi);
        unsigned int kkL = kk - (hS - hH);
        unsigned int bin = (unsigned int)__shfl((int)binL, src, 64);
        kk = (unsigned int)__shfl((int)kkL, src, 64);
        unsigned int tot = (unsigned int)__shfl((int)hH, src, 64);
        prefix = (prefix << 8) | bin;
        if (level == 3) totEq = tot;  // #candidate keys exactly equal to Kth
    }
    const unsigned int Kth = prefix;
    const unsigned int nEq = kk;  // #equal keys to keep (lowest index first)

    // block-uniform "ties straddle boundary" flag
    // (keys == Kth are all > pivKey, so totEq counts ALL equal keys)
    if (tr == 0) { s_tot[r] = totEq; s_fkk[r] = nEq; }
    __syncthreads();
    bool needRank = false;
#pragma unroll
    for (int rr = 0; rr < RPB; ++rr) needRank |= (s_tot[rr] != s_fkk[rr]);

    unsigned int m_eq = 0u, m_gt = 0u;
#pragma unroll
    for (int s2 = 0; s2 < 32; ++s2) {
        unsigned int k = keys[s2];
        if (k == Kth) m_eq |= (1u << s2);
        if (k > Kth) m_gt |= (1u << s2);
    }

    unsigned int actEq = m_eq;  // fast path: all equal keys active
    if (needRank) {             // rare; block-uniform so barriers are safe
#pragma unroll
        for (int j = 0; j < 8; ++j) {
            unsigned int tot = 0u;
#pragma unroll
            for (int i = 0; i < 4; ++i) {
                unsigned long long b2 = __ballot((m_eq >> (j * 4 + i)) & 1u);
                tot += (unsigned int)__popcll(b2);
            }
            if (lane == 0) cntJW[r][j][wrow] = tot;
        }
        __syncthreads();
        const unsigned long long lt = (1ull << lane) - 1ull;
        unsigned int A = 0u;       // equals in chunks j' < j (this row)
        unsigned int newEq = 0u;
#pragma unroll
        for (int j = 0; j < 8; ++j) {
            unsigned int Wlt = 0u, rowTot = 0u;
#pragma unroll
            for (int w = 0; w < 4; ++w) {
                unsigned int cw = cntJW[r][j][w];
                rowTot += cw;
                if (w < wrow) Wlt += cw;
            }
            unsigned int pl[4];
#pragma unroll
            for (int i = 0; i < 4; ++i) {
                unsigned long long b2 = __ballot((m_eq >> (j * 4 + i)) & 1u);
                pl[i] = (unsigned int)__popcll(b2 & lt);
            }
            unsigned int lanesBelow = pl[0] + pl[1] + pl[2] + pl[3];
            unsigned int own = 0u;
#pragma unroll
            for (int i = 0; i < 4; ++i) {
                bool mine = (m_eq >> (j * 4 + i)) & 1u;
                if (mine) {
                    unsigned int rank = A + Wlt + lanesBelow + own;
                    if (rank < nEq) newEq |= (1u << (j * 4 + i));
                    ++own;
                }
            }
            A += rowTot;
        }
        actEq = newEq;
    }

    // ---- output pass: re-read BT (L2/L3-hot), NT float4 streams
    floatx4* O4 = (floatx4*)(out + base);
    floatx4* BO4 = (floatx4*)(boost_out + base);
    unsigned int cntAct = 0u;
#pragma unroll
    for (int j = 0; j < 8; ++j) {
        int u = j * TPR + tr;
        floatx4 ov, bv2;
        float4 bv;
        if (MODE == 0) bv = BT4[u];
        float bs[4] = {bv.x, bv.y, bv.z, bv.w};
#pragma unroll
        for (int i = 0; i < 4; ++i) {
            int s2 = j * 4 + i;
            bool act = (((m_gt >> s2) & 1u) | ((actEq >> s2) & 1u)) != 0u;
            if (MODE == 0) {
                bool on = act && (((m_sg >> s2) & 1u) != 0u);
                ov[i] = on ? 1.0f : 0.0f;
                cntAct += on ? 1u : 0u;
                bv2[i] = act ? 0.0f : (bs[i] + c);
            } else {
                ov[i] = act ? 1.0f : 0.0f;
            }
        }
        if (rowValid) {
            __builtin_nontemporal_store(ov, &O4[u]);
            if (MODE == 0) {
                __builtin_nontemporal_store(bv2, &BO4[u]);
            }
        }
    }
    if (MODE == 0) {
        for (int d = 32; d >= 1; d >>= 1) cntAct += __shfl_xor(cntAct, d, 64);
        if (lane == 0 && rowValid) atomicAdd(&scnt, cntAct);
        __syncthreads();
        if (t == 0) atomicAdd(count, scnt);
    }
}

extern "C" void kernel_launch(void* const* d_in, const int* in_sizes, int n_in,
                              void* d_out, int out_size, void* d_ws, size_t ws_size,
                              hipStream_t stream) {
    const float* T = (const float*)d_in[0];
    const float* BT = (const float*)d_in[1];
    const float* BP = (const float*)d_in[2];
    const int B = in_sizes[0] / E;  // 4096
    float* out = (float*)d_out;
    float* boost_out = out + (size_t)B * E;
    unsigned int* ws = (unsigned int*)d_ws;

    hipLaunchKernelGGL(init_ws_kernel, dim3(1), dim3(1), 0, stream, ws);

    const int n4 = in_sizes[0] / 4;
    hipLaunchKernelGGL(gmax_kernel, dim3(2048), dim3(256), 0, stream, T, ws, n4);

    const int nblk = (B + RPB - 1) / RPB;
    hipLaunchKernelGGL((select_kernel<0>), dim3(nblk), dim3(TPB), 0, stream,
                       T, BT, BP, ws, out, boost_out, ws + 1, B);
    // all-zero fallback (general semantics); every block early-exits when count != 0
    hipLaunchKernelGGL((select_kernel<1>), dim3(nblk), dim3(TPB), 0, stream,
                       T, BT, BP, ws, out, boost_out, ws + 1, B);
}

// Round 11
// 161.670 us; speedup vs baseline: 1.0538x; 1.0538x over previous
//
#include <hip/hip_runtime.h>
#include <stdint.h>

#define E 8192
#define KACT 164           // ceil(0.02 * 8192)
#define TPR 256            // threads per row
#define RPB 2              // rows per block
#define TPB (TPR * RPB)    // 512

typedef float floatx4 __attribute__((ext_vector_type(4)));  // NT-store-compatible

__device__ __forceinline__ unsigned int keyxform(unsigned int s) {
    return (s & 0x80000000u) ? ~s : (s | 0x80000000u);
}

// ---------------- ws layout: [0]=max bits (uint, >=0 float), [1]=winner count
__global__ void init_ws_kernel(unsigned int* ws) {
    ws[0] = 0u;
    ws[1] = 0u;
}

// ---------------- global max(0, max(tensor)) -> ws[0] as uint bits
__global__ void __launch_bounds__(256) gmax_kernel(const float* __restrict__ T,
                                                   unsigned int* __restrict__ ws,
                                                   int n4) {
    __shared__ float wmax[4];
    int tid = blockIdx.x * 256 + threadIdx.x;
    int stride = gridDim.x * 256;
    const float4* T4 = (const float4*)T;
    float m = 0.0f;  // clamp at 0 built in
    for (int i = tid; i < n4; i += stride) {
        float4 v = T4[i];
        m = fmaxf(m, fmaxf(fmaxf(v.x, v.y), fmaxf(v.z, v.w)));
    }
    for (int d = 32; d >= 1; d >>= 1) m = fmaxf(m, __shfl_xor(m, d, 64));
    int lane = threadIdx.x & 63, wid = threadIdx.x >> 6;
    if (lane == 0) wmax[wid] = m;
    __syncthreads();
    if (threadIdx.x == 0) {
        m = fmaxf(fmaxf(wmax[0], wmax[1]), fmaxf(wmax[2], wmax[3]));
        atomicMax(ws, __float_as_uint(m));
    }
}

// ---------------- per-row top-k select + outputs, 2 rows per 512-thread block
// Keys register-resident. boost_out streamed in the LOAD pass (b = bt + c);
// output pass only scatter-zeros the ~164 active positions per row (owner
// thread rewrites -> same-thread ordering). Statistical pivot (mu + a*sigma)
// with exact count check + fallback ladder prunes the histogram to ~400
// candidates/row (exact for any data).
template <int MODE>
__global__ void __launch_bounds__(TPB, 4) select_kernel(
    const float* __restrict__ T, const float* __restrict__ BT,
    const float* __restrict__ BP, const unsigned int* __restrict__ ws_max,
    float* __restrict__ out, float* __restrict__ boost_out,
    unsigned int* __restrict__ count, int Btot) {

    __shared__ unsigned int hist[4][RPB][256];  // one buffer per radix level
    __shared__ float sred[RPB][4][2];           // per-wave sum, sumsq
    __shared__ unsigned int scw[RPB][4][2];     // per-wave candidate counts
    __shared__ unsigned int s_tot[RPB], s_fkk[RPB];
    __shared__ unsigned int cntJW[RPB][8][4];
    __shared__ unsigned int scnt;

    if (MODE == 1) {
        if (count[0] != 0u) return;  // uniform: fallback not needed
    }

    const int t = threadIdx.x;
    const int r = t >> 8;           // row within block
    const int tr = t & (TPR - 1);   // thread within row
    const int lane = t & 63;
    const int wrow = (t >> 6) & 3;  // wave within row group
    int row = blockIdx.x * RPB + r;
    const bool rowValid = (row < Btot);
    if (!rowValid) row = Btot - 1;  // safe addresses; stores predicated
    const size_t base = (size_t)row * E;

    if (t == 0) scnt = 0u;
    // zero all 4 hist buffers once (4*2*256 = 2048 uints = 512 uint4, 512 thr)
    {
        uint4 z = {0u, 0u, 0u, 0u};
        ((uint4*)hist)[t] = z;
    }

    const float c = __uint_as_float(ws_max[0]) * BP[0];

    const float4* T4 = (const float4*)(T + base);
    const float4* BT4 = (const float4*)(BT + base);
    float4* BO4w = (float4*)(boost_out + base);

    unsigned int keys[32];
    unsigned int m_sg = 0u;  // x>0 bitmask over 32 owned elements
    float bsum = 0.0f, bsq = 0.0f;

    // ---- load pass: keys to registers + stats + stream boost_out = b
#pragma unroll
    for (int j = 0; j < 8; ++j) {
        int u = j * TPR + tr;
        float4 tv = T4[u];
        float4 bv = BT4[u];
        float xs[4] = {tv.x, tv.y, tv.z, tv.w};
        float bs[4] = {bv.x, bv.y, bv.z, bv.w};
        float bvals[4];
#pragma unroll
        for (int i = 0; i < 4; ++i) {
            float b = bs[i] + c;
            float x = xs[i];
            float boosted = (x > 0.0f ? x : 0.0f) + b;
            keys[j * 4 + i] = keyxform(__float_as_uint(boosted));
            if (x > 0.0f) m_sg |= (1u << (j * 4 + i));
            bvals[i] = b;
            bsum += boosted;
            bsq += boosted * boosted;
        }
        if (MODE == 0 && rowValid) {
            float4 bw = {bvals[0], bvals[1], bvals[2], bvals[3]};
            BO4w[u] = bw;  // regular store: keeps line L2-warm for scatter-zero
        }
    }

    // ---- per-row mean/sigma (register + shfl reduce, 1 barrier)
#pragma unroll
    for (int d = 32; d >= 1; d >>= 1) {
        bsum += __shfl_xor(bsum, d, 64);
        bsq += __shfl_xor(bsq, d, 64);
    }
    if (lane == 0) { sred[r][wrow][0] = bsum; sred[r][wrow][1] = bsq; }
    __syncthreads();  // also covers hist zeroing + scnt
    float S = 0.0f, Q = 0.0f;
#pragma unroll
    for (int w = 0; w < 4; ++w) { S += sred[r][w][0]; Q += sred[r][w][1]; }
    const float mu = S * (1.0f / E);
    const float sig = sqrtf(fmaxf(Q * (1.0f / E) - mu * mu, 0.0f));
    const unsigned int V1k = keyxform(__float_as_uint(mu + 2.2f * sig));
    const unsigned int V2k = keyxform(__float_as_uint(mu + 0.8f * sig));

    // ---- exact candidate counts for both pivots (register compares)
    unsigned int c1 = 0u, c2 = 0u;
#pragma unroll
    for (int s2 = 0; s2 < 32; ++s2) {
        c1 += (keys[s2] > V1k) ? 1u : 0u;
        c2 += (keys[s2] > V2k) ? 1u : 0u;
    }
#pragma unroll
    for (int d = 32; d >= 1; d >>= 1) {
        c1 += __shfl_xor(c1, d, 64);
        c2 += __shfl_xor(c2, d, 64);
    }
    if (lane == 0) { scw[r][wrow][0] = c1; scw[r][wrow][1] = c2; }
    __syncthreads();
    unsigned int n1 = 0u, n2 = 0u;
#pragma unroll
    for (int w = 0; w < 4; ++w) { n1 += scw[r][w][0]; n2 += scw[r][w][1]; }
    // pivot ladder: V1 if enough candidates, else V2, else full (exact)
    const unsigned int pivKey =
        (n1 >= KACT) ? V1k : ((n2 >= KACT) ? V2k : 0u);

    // ---- radix select among candidates: 4 x 8-bit levels, exact
    unsigned int prefix = 0u;
    unsigned int kk = KACT;
    unsigned int totEq = 0u;
#pragma unroll
    for (int level = 0; level < 4; ++level) {
        const int shift = 24 - 8 * level;
        unsigned int* H = &hist[level][r][0];
#pragma unroll
        for (int s2 = 0; s2 < 32; ++s2) {
            unsigned int key = keys[s2];
            bool match = (key > pivKey) &&
                         ((level == 0) || ((key >> (shift + 8)) == prefix));
            if (match) atomicAdd(&H[(key >> shift) & 255u], 1u);
        }
        __syncthreads();  // single barrier per level (buffers pre-zeroed)

        // wave-autonomous suffix scan: lane reads bins 4*lane .. 4*lane+3
        const uint4* H4 = (const uint4*)H;
        uint4 h4 = H4[lane];
        unsigned int sf3 = h4.w;
        unsigned int sf2 = h4.z + sf3;
        unsigned int sf1 = h4.y + sf2;
        unsigned int sf0 = h4.x + sf1;  // suffix within quad (incl.)
        unsigned int v = sf0;           // quad total
#pragma unroll
        for (int d = 1; d < 64; d <<= 1) {
            unsigned int x = __shfl_down(v, d, 64);
            if (lane + d < 64) v += x;
        }
        unsigned int exclAbove = v - sf0;  // sum of quads in lanes > lane
        unsigned int S0 = sf0 + exclAbove, S1 = sf1 + exclAbove;
        unsigned int S2 = sf2 + exclAbove, S3 = sf3 + exclAbove;
        // unique bin where cumulative (from top) crosses kk
        int hi = -1;
        unsigned int hS = 0u, hH = 0u;
        if (S3 >= kk && S3 - h4.w < kk) { hi = 3; hS = S3; hH = h4.w; }
        if (S2 >= kk && S2 - h4.z < kk) { hi = 2; hS = S2; hH = h4.z; }
        if (S1 >= kk && S1 - h4.y < kk) { hi = 1; hS = S1; hH = h4.y; }
        if (S0 >= kk && S0 - h4.x < kk) { hi = 0; hS = S0; hH = h4.x; }
        unsigned long long bal = __ballot(hi >= 0);
        int src = __ffsll((long long)bal) - 1;
        unsigned int binL = (unsigned int)(4 * lane + hi);
        unsigned int kkL = kk - (hS - hH);
        unsigned int bin = (unsigned int)__shfl((int)binL, src, 64);
        kk = (unsigned int)__shfl((int)kkL, src, 64);
        unsigned int tot = (unsigned int)__shfl((int)hH, src, 64);
        prefix = (prefix << 8) | bin;
        if (level == 3) totEq = tot;  // #candidate keys exactly equal to Kth
    }
    const unsigned int Kth = prefix;
    const unsigned int nEq = kk;  // #equal keys to keep (lowest index first)

    // block-uniform "ties straddle boundary" flag
    // (keys == Kth are all > pivKey, so totEq counts ALL equal keys)
    if (tr == 0) { s_tot[r] = totEq; s_fkk[r] = nEq; }
    __syncthreads();
    const bool needRank = (s_tot[0] != s_fkk[0]) || (s_tot[1] != s_fkk[1]);

    unsigned int m_eq = 0u, m_gt = 0u;
#pragma unroll
    for (int s2 = 0; s2 < 32; ++s2) {
        unsigned int k = keys[s2];
        if (k == Kth) m_eq |= (1u << s2);
        if (k > Kth) m_gt |= (1u << s2);
    }

    unsigned int actEq = m_eq;  // fast path: all equal keys active
    if (needRank) {             // rare; block-uniform so barriers are safe
#pragma unroll
        for (int j = 0; j < 8; ++j) {
            unsigned int tot = 0u;
#pragma unroll
            for (int i = 0; i < 4; ++i) {
                unsigned long long b2 = __ballot((m_eq >> (j * 4 + i)) & 1u);
                tot += (unsigned int)__popcll(b2);
            }
            if (lane == 0) cntJW[r][j][wrow] = tot;
        }
        __syncthreads();
        const unsigned long long lt = (1ull << lane) - 1ull;
        unsigned int A = 0u;       // equals in chunks j' < j (this row)
        unsigned int newEq = 0u;
#pragma unroll
        for (int j = 0; j < 8; ++j) {
            unsigned int Wlt = 0u, rowTot = 0u;
#pragma unroll
            for (int w = 0; w < 4; ++w) {
                unsigned int cw = cntJW[r][j][w];
                rowTot += cw;
                if (w < wrow) Wlt += cw;
            }
            unsigned int pl[4];
#pragma unroll
            for (int i = 0; i < 4; ++i) {
                unsigned long long b2 = __ballot((m_eq >> (j * 4 + i)) & 1u);
                pl[i] = (unsigned int)__popcll(b2 & lt);
            }
            unsigned int lanesBelow = pl[0] + pl[1] + pl[2] + pl[3];
            unsigned int own = 0u;
#pragma unroll
            for (int i = 0; i < 4; ++i) {
                bool mine = (m_eq >> (j * 4 + i)) & 1u;
                if (mine) {
                    unsigned int rank = A + Wlt + lanesBelow + own;
                    if (rank < nEq) newEq |= (1u << (j * 4 + i));
                    ++own;
                }
            }
            A += rowTot;
        }
        actEq = newEq;
    }

    // ---- output pass: NT out stream; scatter-zero active boost positions
    floatx4* O4 = (floatx4*)(out + base);
    unsigned int cntAct = 0u;
#pragma unroll
    for (int j = 0; j < 8; ++j) {
        int u = j * TPR + tr;
        floatx4 ov;
#pragma unroll
        for (int i = 0; i < 4; ++i) {
            int s2 = j * 4 + i;
            bool act = (((m_gt >> s2) & 1u) | ((actEq >> s2) & 1u)) != 0u;
            if (MODE == 0) {
                bool on = act && (((m_sg >> s2) & 1u) != 0u);
                ov[i] = on ? 1.0f : 0.0f;
                cntAct += on ? 1u : 0u;
                if (act && rowValid) boost_out[base + (size_t)(4 * u + i)] = 0.0f;
            } else {
                ov[i] = act ? 1.0f : 0.0f;
            }
        }
        if (rowValid) {
            __builtin_nontemporal_store(ov, &O4[u]);
        }
    }
    if (MODE == 0) {
        for (int d = 32; d >= 1; d >>= 1) cntAct += __shfl_xor(cntAct, d, 64);
        if (lane == 0 && rowValid) atomicAdd(&scnt, cntAct);
        __syncthreads();
        if (t == 0) atomicAdd(count, scnt);
    }
}

extern "C" void kernel_launch(void* const* d_in, const int* in_sizes, int n_in,
                              void* d_out, int out_size, void* d_ws, size_t ws_size,
                              hipStream_t stream) {
    const float* T = (const float*)d_in[0];
    const float* BT = (const float*)d_in[1];
    const float* BP = (const float*)d_in[2];
    const int B = in_sizes[0] / E;  // 4096
    float* out = (float*)d_out;
    float* boost_out = out + (size_t)B * E;
    unsigned int* ws = (unsigned int*)d_ws;

    hipLaunchKernelGGL(init_ws_kernel, dim3(1), dim3(1), 0, stream, ws);

    const int n4 = in_sizes[0] / 4;
    hipLaunchKernelGGL(gmax_kernel, dim3(2048), dim3(256), 0, stream, T, ws, n4);

    const int nblk = (B + RPB - 1) / RPB;
    hipLaunchKernelGGL((select_kernel<0>), dim3(nblk), dim3(TPB), 0, stream,
                       T, BT, BP, ws, out, boost_out, ws + 1, B);
    // all-zero fallback (general semantics); every block early-exits when count != 0
    hipLaunchKernelGGL((select_kernel<1>), dim3(nblk), dim3(TPB), 0, stream,
                       T, BT, BP, ws, out, boost_out, ws + 1, B);
}

// Round 12
// 143.264 us; speedup vs baseline: 1.1892x; 1.1285x over previous
//
#include <hip/hip_runtime.h>
#include <stdint.h>

#define E 8192
#define KACT 164           // ceil(0.02 * 8192)
#define TPR 256            // threads per row
#define RPB 2              // rows per block
#define TPB (TPR * RPB)    // 512

typedef float floatx4 __attribute__((ext_vector_type(4)));  // NT-store-compatible

__device__ __forceinline__ unsigned int keyxform(unsigned int s) {
    return (s & 0x80000000u) ? ~s : (s | 0x80000000u);
}

// ---------------- ws layout: [0]=max bits (uint, >=0 float), [1]=winner count
__global__ void init_ws_kernel(unsigned int* ws) {
    ws[0] = 0u;
    ws[1] = 0u;
}

// ---------------- global max(0, max(tensor)) -> ws[0] as uint bits
__global__ void __launch_bounds__(256) gmax_kernel(const float* __restrict__ T,
                                                   unsigned int* __restrict__ ws,
                                                   int n4) {
    __shared__ float wmax[4];
    int tid = blockIdx.x * 256 + threadIdx.x;
    int stride = gridDim.x * 256;
    const float4* T4 = (const float4*)T;
    float m = 0.0f;  // clamp at 0 built in
    for (int i = tid; i < n4; i += stride) {
        float4 v = T4[i];
        m = fmaxf(m, fmaxf(fmaxf(v.x, v.y), fmaxf(v.z, v.w)));
    }
    for (int d = 32; d >= 1; d >>= 1) m = fmaxf(m, __shfl_xor(m, d, 64));
    int lane = threadIdx.x & 63, wid = threadIdx.x >> 6;
    if (lane == 0) wmax[wid] = m;
    __syncthreads();
    if (threadIdx.x == 0) {
        m = fmaxf(fmaxf(wmax[0], wmax[1]), fmaxf(wmax[2], wmax[3]));
        atomicMax(ws, __float_as_uint(m));
    }
}

// ---------------- per-row top-k select + outputs, 2 rows per 512-thread block
// Keys register-resident; boost values staged in LDS during the load pass
// (64 KB/block, stride-1 float4 = conflict-free) so the output pass needs no
// BT re-read. Statistical pivot (mu + a*sigma) with exact count check +
// fallback ladder prunes the histogram to ~400 candidates/row (exact for any
// data: candidate set provably contains the k-th key when count >= KACT,
// else the pivot relaxes down the ladder to 0 = full set).
template <int MODE>
__global__ void __launch_bounds__(TPB, 4) select_kernel(
    const float* __restrict__ T, const float* __restrict__ BT,
    const float* __restrict__ BP, const unsigned int* __restrict__ ws_max,
    float* __restrict__ out, float* __restrict__ boost_out,
    unsigned int* __restrict__ count, int Btot) {

    __shared__ floatx4 bstage[RPB][E / 4];      // staged boost values (64 KB)
    __shared__ unsigned int hist[4][RPB][256];  // one buffer per radix level
    __shared__ float sred[RPB][4][2];           // per-wave sum, sumsq
    __shared__ unsigned int scw[RPB][4][2];     // per-wave candidate counts
    __shared__ unsigned int s_tot[RPB], s_fkk[RPB];
    __shared__ unsigned int cntJW[RPB][8][4];
    __shared__ unsigned int scnt;

    if (MODE == 1) {
        if (count[0] != 0u) return;  // uniform: fallback not needed
    }

    const int t = threadIdx.x;
    const int r = t >> 8;           // row within block
    const int tr = t & (TPR - 1);   // thread within row
    const int lane = t & 63;
    const int wrow = (t >> 6) & 3;  // wave within row group
    int row = blockIdx.x * RPB + r;
    const bool rowValid = (row < Btot);
    if (!rowValid) row = Btot - 1;  // safe addresses; stores predicated
    const size_t base = (size_t)row * E;

    if (t == 0) scnt = 0u;
    // zero all 4 hist buffers once (4*2*256 = 2048 uints = 512 uint4, 512 thr)
    {
        uint4 z = {0u, 0u, 0u, 0u};
        ((uint4*)hist)[t] = z;
    }

    const float c = __uint_as_float(ws_max[0]) * BP[0];

    const float4* T4 = (const float4*)(T + base);
    const float4* BT4 = (const float4*)(BT + base);

    unsigned int keys[32];
    unsigned int m_sg = 0u;  // x>0 bitmask over 32 owned elements
    float bsum = 0.0f, bsq = 0.0f;

    // ---- load pass: keys to registers + stats; stage b in LDS
#pragma unroll
    for (int j = 0; j < 8; ++j) {
        int u = j * TPR + tr;
        float4 tv = T4[u];
        float4 bv = BT4[u];
        float xs[4] = {tv.x, tv.y, tv.z, tv.w};
        float bs[4] = {bv.x, bv.y, bv.z, bv.w};
        floatx4 bq;
#pragma unroll
        for (int i = 0; i < 4; ++i) {
            float b = bs[i] + c;
            float x = xs[i];
            float boosted = (x > 0.0f ? x : 0.0f) + b;
            keys[j * 4 + i] = keyxform(__float_as_uint(boosted));
            if (x > 0.0f) m_sg |= (1u << (j * 4 + i));
            bq[i] = b;
            bsum += boosted;
            bsq += boosted * boosted;
        }
        if (MODE == 0) bstage[r][u] = bq;
    }

    // ---- per-row mean/sigma (register + shfl reduce, 1 barrier)
#pragma unroll
    for (int d = 32; d >= 1; d >>= 1) {
        bsum += __shfl_xor(bsum, d, 64);
        bsq += __shfl_xor(bsq, d, 64);
    }
    if (lane == 0) { sred[r][wrow][0] = bsum; sred[r][wrow][1] = bsq; }
    __syncthreads();  // also covers hist zeroing + scnt + bstage writes
    float S = 0.0f, Q = 0.0f;
#pragma unroll
    for (int w = 0; w < 4; ++w) { S += sred[r][w][0]; Q += sred[r][w][1]; }
    const float mu = S * (1.0f / E);
    const float sig = sqrtf(fmaxf(Q * (1.0f / E) - mu * mu, 0.0f));
    const unsigned int V1k = keyxform(__float_as_uint(mu + 2.2f * sig));
    const unsigned int V2k = keyxform(__float_as_uint(mu + 0.8f * sig));

    // ---- exact candidate counts for both pivots (register compares)
    unsigned int c1 = 0u, c2 = 0u;
#pragma unroll
    for (int s2 = 0; s2 < 32; ++s2) {
        c1 += (keys[s2] > V1k) ? 1u : 0u;
        c2 += (keys[s2] > V2k) ? 1u : 0u;
    }
#pragma unroll
    for (int d = 32; d >= 1; d >>= 1) {
        c1 += __shfl_xor(c1, d, 64);
        c2 += __shfl_xor(c2, d, 64);
    }
    if (lane == 0) { scw[r][wrow][0] = c1; scw[r][wrow][1] = c2; }
    __syncthreads();
    unsigned int n1 = 0u, n2 = 0u;
#pragma unroll
    for (int w = 0; w < 4; ++w) { n1 += scw[r][w][0]; n2 += scw[r][w][1]; }
    // pivot ladder: V1 if enough candidates, else V2, else full (exact)
    const unsigned int pivKey =
        (n1 >= KACT) ? V1k : ((n2 >= KACT) ? V2k : 0u);

    // ---- radix select among candidates: 4 x 8-bit levels, exact
    unsigned int prefix = 0u;
    unsigned int kk = KACT;
    unsigned int totEq = 0u;
#pragma unroll
    for (int level = 0; level < 4; ++level) {
        const int shift = 24 - 8 * level;
        unsigned int* H = &hist[level][r][0];
#pragma unroll
        for (int s2 = 0; s2 < 32; ++s2) {
            unsigned int key = keys[s2];
            bool match = (key > pivKey) &&
                         ((level == 0) || ((key >> (shift + 8)) == prefix));
            if (match) atomicAdd(&H[(key >> shift) & 255u], 1u);
        }
        __syncthreads();  // single barrier per level (buffers pre-zeroed)

        // wave-autonomous suffix scan: lane reads bins 4*lane .. 4*lane+3
        const uint4* H4 = (const uint4*)H;
        uint4 h4 = H4[lane];
        unsigned int sf3 = h4.w;
        unsigned int sf2 = h4.z + sf3;
        unsigned int sf1 = h4.y + sf2;
        unsigned int sf0 = h4.x + sf1;  // suffix within quad (incl.)
        unsigned int v = sf0;           // quad total
#pragma unroll
        for (int d = 1; d < 64; d <<= 1) {
            unsigned int x = __shfl_down(v, d, 64);
            if (lane + d < 64) v += x;
        }
        unsigned int exclAbove = v - sf0;  // sum of quads in lanes > lane
        unsigned int S0 = sf0 + exclAbove, S1 = sf1 + exclAbove;
        unsigned int S2 = sf2 + exclAbove, S3 = sf3 + exclAbove;
        // unique bin where cumulative (from top) crosses kk
        int hi = -1;
        unsigned int hS = 0u, hH = 0u;
        if (S3 >= kk && S3 - h4.w < kk) { hi = 3; hS = S3; hH = h4.w; }
        if (S2 >= kk && S2 - h4.z < kk) { hi = 2; hS = S2; hH = h4.z; }
        if (S1 >= kk && S1 - h4.y < kk) { hi = 1; hS = S1; hH = h4.y; }
        if (S0 >= kk && S0 - h4.x < kk) { hi = 0; hS = S0; hH = h4.x; }
        unsigned long long bal = __ballot(hi >= 0);
        int src = __ffsll((long long)bal) - 1;
        unsigned int binL = (unsigned int)(4 * lane + hi);
        unsigned int kkL = kk - (hS - hH);
        unsigned int bin = (unsigned int)__shfl((int)binL, src, 64);
        kk = (unsigned int)__shfl((int)kkL, src, 64);
        unsigned int tot = (unsigned int)__shfl((int)hH, src, 64);
        prefix = (prefix << 8) | bin;
        if (level == 3) totEq = tot;  // #candidate keys exactly equal to Kth
    }
    const unsigned int Kth = prefix;
    const unsigned int nEq = kk;  // #equal keys to keep (lowest index first)

    // block-uniform "ties straddle boundary" flag
    // (keys == Kth are all > pivKey, so totEq counts ALL equal keys)
    if (tr == 0) { s_tot[r] = totEq; s_fkk[r] = nEq; }
    __syncthreads();
    const bool needRank = (s_tot[0] != s_fkk[0]) || (s_tot[1] != s_fkk[1]);

    unsigned int m_eq = 0u, m_gt = 0u;
#pragma unroll
    for (int s2 = 0; s2 < 32; ++s2) {
        unsigned int k = keys[s2];
        if (k == Kth) m_eq |= (1u << s2);
        if (k > Kth) m_gt |= (1u << s2);
    }

    unsigned int actEq = m_eq;  // fast path: all equal keys active
    if (needRank) {             // rare; block-uniform so barriers are safe
#pragma unroll
        for (int j = 0; j < 8; ++j) {
            unsigned int tot = 0u;
#pragma unroll
            for (int i = 0; i < 4; ++i) {
                unsigned long long b2 = __ballot((m_eq >> (j * 4 + i)) & 1u);
                tot += (unsigned int)__popcll(b2);
            }
            if (lane == 0) cntJW[r][j][wrow] = tot;
        }
        __syncthreads();
        const unsigned long long lt = (1ull << lane) - 1ull;
        unsigned int A = 0u;       // equals in chunks j' < j (this row)
        unsigned int newEq = 0u;
#pragma unroll
        for (int j = 0; j < 8; ++j) {
            unsigned int Wlt = 0u, rowTot = 0u;
#pragma unroll
            for (int w = 0; w < 4; ++w) {
                unsigned int cw = cntJW[r][j][w];
                rowTot += cw;
                if (w < wrow) Wlt += cw;
            }
            unsigned int pl[4];
#pragma unroll
            for (int i = 0; i < 4; ++i) {
                unsigned long long b2 = __ballot((m_eq >> (j * 4 + i)) & 1u);
                pl[i] = (unsigned int)__popcll(b2 & lt);
            }
            unsigned int lanesBelow = pl[0] + pl[1] + pl[2] + pl[3];
            unsigned int own = 0u;
#pragma unroll
            for (int i = 0; i < 4; ++i) {
                bool mine = (m_eq >> (j * 4 + i)) & 1u;
                if (mine) {
                    unsigned int rank = A + Wlt + lanesBelow + own;
                    if (rank < nEq) newEq |= (1u << (j * 4 + i));
                    ++own;
                }
            }
            A += rowTot;
        }
        actEq = newEq;
    }

    // ---- output pass: NT float4 streams, boost from LDS stage
    floatx4* O4 = (floatx4*)(out + base);
    floatx4* BO4 = (floatx4*)(boost_out + base);
    unsigned int cntAct = 0u;
#pragma unroll
    for (int j = 0; j < 8; ++j) {
        int u = j * TPR + tr;
        floatx4 ov, bv2;
        floatx4 bq;
        if (MODE == 0) bq = bstage[r][u];
#pragma unroll
        for (int i = 0; i < 4; ++i) {
            int s2 = j * 4 + i;
            bool act = (((m_gt >> s2) & 1u) | ((actEq >> s2) & 1u)) != 0u;
            if (MODE == 0) {
                bool on = act && (((m_sg >> s2) & 1u) != 0u);
                ov[i] = on ? 1.0f : 0.0f;
                cntAct += on ? 1u : 0u;
                bv2[i] = act ? 0.0f : bq[i];
            } else {
                ov[i] = act ? 1.0f : 0.0f;
            }
        }
        if (rowValid) {
            __builtin_nontemporal_store(ov, &O4[u]);
            if (MODE == 0) {
                __builtin_nontemporal_store(bv2, &BO4[u]);
            }
        }
    }
    if (MODE == 0) {
        for (int d = 32; d >= 1; d >>= 1) cntAct += __shfl_xor(cntAct, d, 64);
        if (lane == 0 && rowValid) atomicAdd(&scnt, cntAct);
        __syncthreads();
        if (t == 0) atomicAdd(count, scnt);
    }
}

extern "C" void kernel_launch(void* const* d_in, const int* in_sizes, int n_in,
                              void* d_out, int out_size, void* d_ws, size_t ws_size,
                              hipStream_t stream) {
    const float* T = (const float*)d_in[0];
    const float* BT = (const float*)d_in[1];
    const float* BP = (const float*)d_in[2];
    const int B = in_sizes[0] / E;  // 4096
    float* out = (float*)d_out;
    float* boost_out = out + (size_t)B * E;
    unsigned int* ws = (unsigned int*)d_ws;

    hipLaunchKernelGGL(init_ws_kernel, dim3(1), dim3(1), 0, stream, ws);

    const int n4 = in_sizes[0] / 4;
    hipLaunchKernelGGL(gmax_kernel, dim3(2048), dim3(256), 0, stream, T, ws, n4);

    const int nblk = (B + RPB - 1) / RPB;
    hipLaunchKernelGGL((select_kernel<0>), dim3(nblk), dim3(TPB), 0, stream,
                       T, BT, BP, ws, out, boost_out, ws + 1, B);
    // all-zero fallback (general semantics); every block early-exits when count != 0
    hipLaunchKernelGGL((select_kernel<1>), dim3(nblk), dim3(TPB), 0, stream,
                       T, BT, BP, ws, out, boost_out, ws + 1, B);
}

// Round 13
// 128.177 us; speedup vs baseline: 1.3292x; 1.1177x over previous
//
#include <hip/hip_runtime.h>
#include <stdint.h>

#define E 8192
#define KACT 164           // ceil(0.02 * 8192)
#define TPR 256            // threads per row
#define RPB 2              // rows per block
#define TPB (TPR * RPB)    // 512
#define WSOFF 64           // ws layout: [0..1] legacy, [WSOFF..+2048) maxima, then counts
#define NSLOT 2048

typedef float floatx4 __attribute__((ext_vector_type(4)));  // NT-store-compatible

__device__ __forceinline__ unsigned int keyxform(unsigned int s) {
    return (s & 0x80000000u) ? ~s : (s | 0x80000000u);
}

// ---------------- legacy init (fallback path only)
__global__ void init_ws_kernel(unsigned int* ws) {
    ws[0] = 0u;
    ws[1] = 0u;
}

// ---------------- global max(0, max(tensor))
// PB=1: per-block maxima to ws[WSOFF+bid] (plain store, no init/atomic)
// PB=0: atomicMax on ws[0] (uint bits, valid since >= 0)
template <int PB>
__global__ void __launch_bounds__(256) gmax_kernel(const float* __restrict__ T,
                                                   unsigned int* __restrict__ ws,
                                                   int n4) {
    __shared__ float wmax[4];
    int tid = blockIdx.x * 256 + threadIdx.x;
    int stride = gridDim.x * 256;
    const float4* T4 = (const float4*)T;
    float m = 0.0f;  // clamp at 0 built in
    for (int i = tid; i < n4; i += stride) {
        float4 v = T4[i];
        m = fmaxf(m, fmaxf(fmaxf(v.x, v.y), fmaxf(v.z, v.w)));
    }
    for (int d = 32; d >= 1; d >>= 1) m = fmaxf(m, __shfl_xor(m, d, 64));
    int lane = threadIdx.x & 63, wid = threadIdx.x >> 6;
    if (lane == 0) wmax[wid] = m;
    __syncthreads();
    if (threadIdx.x == 0) {
        m = fmaxf(fmaxf(wmax[0], wmax[1]), fmaxf(wmax[2], wmax[3]));
        if (PB) ((float*)ws)[WSOFF + blockIdx.x] = m;
        else atomicMax(ws, __float_as_uint(m));
    }
}

// ---------------- per-row top-k select + outputs, 2 rows per 512-thread block
// Keys register-resident; boost staged in LDS (64 KB) so no BT re-read.
// Statistical pivot (mu + a*sigma) + exact count ladder (exact for any data).
// PB=1: c from per-block maxima slots; winner count to per-block slot.
template <int MODE, int PB>
__global__ void __launch_bounds__(TPB, 4) select_kernel(
    const float* __restrict__ T, const float* __restrict__ BT,
    const float* __restrict__ BP, unsigned int* __restrict__ ws,
    float* __restrict__ out, float* __restrict__ boost_out, int Btot) {

    __shared__ floatx4 bstage[RPB][E / 4];      // staged boost values (64 KB)
    __shared__ unsigned int hist[4][RPB][256];  // one buffer per radix level
    __shared__ float sred[RPB][4][2];           // per-wave sum, sumsq
    __shared__ unsigned int scw[RPB][4][2];     // per-wave candidate counts
    __shared__ unsigned int s_tot[RPB], s_fkk[RPB];
    __shared__ unsigned int cntJW[RPB][8][4];
    __shared__ unsigned int scnt;
    __shared__ float gmx[8];
    __shared__ unsigned int anyW[8];

    const int t = threadIdx.x;
    const int lane = t & 63;

    if (MODE == 1) {
        if (PB) {  // reduce 2048 per-block counts: any nonzero -> no fallback
            const uint4* C4 = (const uint4*)(ws + WSOFF + NSLOT);
            uint4 cv = C4[t];
            unsigned int any = cv.x | cv.y | cv.z | cv.w;
            unsigned long long bal = __ballot(any != 0u);
            if (lane == 0) anyW[t >> 6] = (bal != 0ull) ? 1u : 0u;
            __syncthreads();
            unsigned int tot = 0u;
#pragma unroll
            for (int w = 0; w < 8; ++w) tot |= anyW[w];
            if (tot) return;  // uniform
            __syncthreads();  // reuse of anyW-free LDS below is fine
        } else {
            if (ws[1] != 0u) return;  // uniform: fallback not needed
        }
    }

    const int r = t >> 8;           // row within block
    const int tr = t & (TPR - 1);   // thread within row
    const int wrow = (t >> 6) & 3;  // wave within row group
    int row = blockIdx.x * RPB + r;
    const bool rowValid = (row < Btot);
    if (!rowValid) row = Btot - 1;  // safe addresses; stores predicated
    const size_t base = (size_t)row * E;

    if (t == 0) scnt = 0u;
    // zero all 4 hist buffers once (4*2*256 = 2048 uints = 512 uint4, 512 thr)
    {
        uint4 z = {0u, 0u, 0u, 0u};
        ((uint4*)hist)[t] = z;
    }

    float c;
    if (PB) {  // reduce 2048 per-block maxima (8 KB, L2-hot) -> c
        const float4* W4 = (const float4*)((const float*)ws + WSOFF);
        float4 w4 = W4[t];
        float m = fmaxf(fmaxf(w4.x, w4.y), fmaxf(w4.z, w4.w));
#pragma unroll
        for (int d = 32; d >= 1; d >>= 1) m = fmaxf(m, __shfl_xor(m, d, 64));
        if (lane == 0) gmx[t >> 6] = m;
        __syncthreads();  // also covers hist zeroing + scnt
        float g = gmx[0];
#pragma unroll
        for (int w = 1; w < 8; ++w) g = fmaxf(g, gmx[w]);
        c = g * BP[0];
    } else {
        c = __uint_as_float(ws[0]) * BP[0];
    }

    const float4* T4 = (const float4*)(T + base);
    const float4* BT4 = (const float4*)(BT + base);

    unsigned int keys[32];
    unsigned int m_sg = 0u;  // x>0 bitmask over 32 owned elements
    float bsum = 0.0f, bsq = 0.0f;

    // ---- load pass: keys to registers + stats; stage b in LDS
#pragma unroll
    for (int j = 0; j < 8; ++j) {
        int u = j * TPR + tr;
        float4 tv = T4[u];
        float4 bv = BT4[u];
        float xs[4] = {tv.x, tv.y, tv.z, tv.w};
        float bs[4] = {bv.x, bv.y, bv.z, bv.w};
        floatx4 bq;
#pragma unroll
        for (int i = 0; i < 4; ++i) {
            float b = bs[i] + c;
            float x = xs[i];
            float boosted = (x > 0.0f ? x : 0.0f) + b;
            keys[j * 4 + i] = keyxform(__float_as_uint(boosted));
            if (x > 0.0f) m_sg |= (1u << (j * 4 + i));
            bq[i] = b;
            bsum += boosted;
            bsq += boosted * boosted;
        }
        if (MODE == 0) bstage[r][u] = bq;
    }

    // ---- per-row mean/sigma (register + shfl reduce, 1 barrier)
#pragma unroll
    for (int d = 32; d >= 1; d >>= 1) {
        bsum += __shfl_xor(bsum, d, 64);
        bsq += __shfl_xor(bsq, d, 64);
    }
    if (lane == 0) { sred[r][wrow][0] = bsum; sred[r][wrow][1] = bsq; }
    __syncthreads();  // covers hist zeroing (PB=0 path) + bstage writes
    float S = 0.0f, Q = 0.0f;
#pragma unroll
    for (int w = 0; w < 4; ++w) { S += sred[r][w][0]; Q += sred[r][w][1]; }
    const float mu = S * (1.0f / E);
    const float sig = sqrtf(fmaxf(Q * (1.0f / E) - mu * mu, 0.0f));
    const unsigned int V1k = keyxform(__float_as_uint(mu + 2.2f * sig));
    const unsigned int V2k = keyxform(__float_as_uint(mu + 0.8f * sig));

    // ---- exact candidate counts for both pivots (register compares)
    unsigned int c1 = 0u, c2 = 0u;
#pragma unroll
    for (int s2 = 0; s2 < 32; ++s2) {
        c1 += (keys[s2] > V1k) ? 1u : 0u;
        c2 += (keys[s2] > V2k) ? 1u : 0u;
    }
#pragma unroll
    for (int d = 32; d >= 1; d >>= 1) {
        c1 += __shfl_xor(c1, d, 64);
        c2 += __shfl_xor(c2, d, 64);
    }
    if (lane == 0) { scw[r][wrow][0] = c1; scw[r][wrow][1] = c2; }
    __syncthreads();
    unsigned int n1 = 0u, n2 = 0u;
#pragma unroll
    for (int w = 0; w < 4; ++w) { n1 += scw[r][w][0]; n2 += scw[r][w][1]; }
    // pivot ladder: V1 if enough candidates, else V2, else full (exact)
    const unsigned int pivKey =
        (n1 >= KACT) ? V1k : ((n2 >= KACT) ? V2k : 0u);

    // ---- radix select among candidates: 4 x 8-bit levels, exact
    unsigned int prefix = 0u;
    unsigned int kk = KACT;
    unsigned int totEq = 0u;
#pragma unroll
    for (int level = 0; level < 4; ++level) {
        const int shift = 24 - 8 * level;
        unsigned int* H = &hist[level][r][0];
#pragma unroll
        for (int s2 = 0; s2 < 32; ++s2) {
            unsigned int key = keys[s2];
            bool match = (key > pivKey) &&
                         ((level == 0) || ((key >> (shift + 8)) == prefix));
            if (match) atomicAdd(&H[(key >> shift) & 255u], 1u);
        }
        __syncthreads();  // single barrier per level (buffers pre-zeroed)

        // wave-autonomous suffix scan: lane reads bins 4*lane .. 4*lane+3
        const uint4* H4 = (const uint4*)H;
        uint4 h4 = H4[lane];
        unsigned int sf3 = h4.w;
        unsigned int sf2 = h4.z + sf3;
        unsigned int sf1 = h4.y + sf2;
        unsigned int sf0 = h4.x + sf1;  // suffix within quad (incl.)
        unsigned int v = sf0;           // quad total
#pragma unroll
        for (int d = 1; d < 64; d <<= 1) {
            unsigned int x = __shfl_down(v, d, 64);
            if (lane + d < 64) v += x;
        }
        unsigned int exclAbove = v - sf0;  // sum of quads in lanes > lane
        unsigned int S0 = sf0 + exclAbove, S1 = sf1 + exclAbove;
        unsigned int S2 = sf2 + exclAbove, S3 = sf3 + exclAbove;
        // unique bin where cumulative (from top) crosses kk
        int hi = -1;
        unsigned int hS = 0u, hH = 0u;
        if (S3 >= kk && S3 - h4.w < kk) { hi = 3; hS = S3; hH = h4.w; }
        if (S2 >= kk && S2 - h4.z < kk) { hi = 2; hS = S2; hH = h4.z; }
        if (S1 >= kk && S1 - h4.y < kk) { hi = 1; hS = S1; hH = h4.y; }
        if (S0 >= kk && S0 - h4.x < kk) { hi = 0; hS = S0; hH = h4.x; }
        unsigned long long bal = __ballot(hi >= 0);
        int src = __ffsll((long long)bal) - 1;
        unsigned int binL = (unsigned int)(4 * lane + hi);
        unsigned int kkL = kk - (hS - hH);
        unsigned int bin = (unsigned int)__shfl((int)binL, src, 64);
        kk = (unsigned int)__shfl((int)kkL, src, 64);
        unsigned int tot = (unsigned int)__shfl((int)hH, src, 64);
        prefix = (prefix << 8) | bin;
        if (level == 3) totEq = tot;  // #candidate keys exactly equal to Kth
    }
    const unsigned int Kth = prefix;
    const unsigned int nEq = kk;  // #equal keys to keep (lowest index first)

    // block-uniform "ties straddle boundary" flag
    // (keys == Kth are all > pivKey, so totEq counts ALL equal keys)
    if (tr == 0) { s_tot[r] = totEq; s_fkk[r] = nEq; }
    __syncthreads();
    const bool needRank = (s_tot[0] != s_fkk[0]) || (s_tot[1] != s_fkk[1]);

    unsigned int m_eq = 0u, m_gt = 0u;
#pragma unroll
    for (int s2 = 0; s2 < 32; ++s2) {
        unsigned int k = keys[s2];
        if (k == Kth) m_eq |= (1u << s2);
        if (k > Kth) m_gt |= (1u << s2);
    }

    unsigned int actEq = m_eq;  // fast path: all equal keys active
    if (needRank) {             // rare; block-uniform so barriers are safe
#pragma unroll
        for (int j = 0; j < 8; ++j) {
            unsigned int tot = 0u;
#pragma unroll
            for (int i = 0; i < 4; ++i) {
                unsigned long long b2 = __ballot((m_eq >> (j * 4 + i)) & 1u);
                tot += (unsigned int)__popcll(b2);
            }
            if (lane == 0) cntJW[r][j][wrow] = tot;
        }
        __syncthreads();
        const unsigned long long lt = (1ull << lane) - 1ull;
        unsigned int A = 0u;       // equals in chunks j' < j (this row)
        unsigned int newEq = 0u;
#pragma unroll
        for (int j = 0; j < 8; ++j) {
            unsigned int Wlt = 0u, rowTot = 0u;
#pragma unroll
            for (int w = 0; w < 4; ++w) {
                unsigned int cw = cntJW[r][j][w];
                rowTot += cw;
                if (w < wrow) Wlt += cw;
            }
            unsigned int pl[4];
#pragma unroll
            for (int i = 0; i < 4; ++i) {
                unsigned long long b2 = __ballot((m_eq >> (j * 4 + i)) & 1u);
                pl[i] = (unsigned int)__popcll(b2 & lt);
            }
            unsigned int lanesBelow = pl[0] + pl[1] + pl[2] + pl[3];
            unsigned int own = 0u;
#pragma unroll
            for (int i = 0; i < 4; ++i) {
                bool mine = (m_eq >> (j * 4 + i)) & 1u;
                if (mine) {
                    unsigned int rank = A + Wlt + lanesBelow + own;
                    if (rank < nEq) newEq |= (1u << (j * 4 + i));
                    ++own;
                }
            }
            A += rowTot;
        }
        actEq = newEq;
    }

    // ---- output pass: NT float4 streams, boost from LDS stage
    floatx4* O4 = (floatx4*)(out + base);
    floatx4* BO4 = (floatx4*)(boost_out + base);
    unsigned int cntAct = 0u;
#pragma unroll
    for (int j = 0; j < 8; ++j) {
        int u = j * TPR + tr;
        floatx4 ov, bv2;
        floatx4 bq;
        if (MODE == 0) bq = bstage[r][u];
#pragma unroll
        for (int i = 0; i < 4; ++i) {
            int s2 = j * 4 + i;
            bool act = (((m_gt >> s2) & 1u) | ((actEq >> s2) & 1u)) != 0u;
            if (MODE == 0) {
                bool on = act && (((m_sg >> s2) & 1u) != 0u);
                ov[i] = on ? 1.0f : 0.0f;
                cntAct += on ? 1u : 0u;
                bv2[i] = act ? 0.0f : bq[i];
            } else {
                ov[i] = act ? 1.0f : 0.0f;
            }
        }
        if (rowValid) {
            __builtin_nontemporal_store(ov, &O4[u]);
            if (MODE == 0) {
                __builtin_nontemporal_store(bv2, &BO4[u]);
            }
        }
    }
    if (MODE == 0) {
        for (int d = 32; d >= 1; d >>= 1) cntAct += __shfl_xor(cntAct, d, 64);
        if (lane == 0 && rowValid) atomicAdd(&scnt, cntAct);
        __syncthreads();
        if (t == 0) {
            if (PB) ws[WSOFF + NSLOT + blockIdx.x] = scnt;  // plain store
            else atomicAdd(ws + 1, scnt);
        }
    }
}

extern "C" void kernel_launch(void* const* d_in, const int* in_sizes, int n_in,
                              void* d_out, int out_size, void* d_ws, size_t ws_size,
                              hipStream_t stream) {
    const float* T = (const float*)d_in[0];
    const float* BT = (const float*)d_in[1];
    const float* BP = (const float*)d_in[2];
    const int B = in_sizes[0] / E;  // 4096
    float* out = (float*)d_out;
    float* boost_out = out + (size_t)B * E;
    unsigned int* ws = (unsigned int*)d_ws;

    const int n4 = in_sizes[0] / 4;
    const int nblk = (B + RPB - 1) / RPB;
    const bool pb = (ws_size >= (WSOFF + 2 * NSLOT) * sizeof(unsigned int)) &&
                    (nblk == NSLOT);

    if (pb) {
        // atomic-free path: per-block maxima + counts via plain stores, no init
        hipLaunchKernelGGL((gmax_kernel<1>), dim3(NSLOT), dim3(256), 0, stream,
                           T, ws, n4);
        hipLaunchKernelGGL((select_kernel<0, 1>), dim3(nblk), dim3(TPB), 0, stream,
                           T, BT, BP, ws, out, boost_out, B);
        hipLaunchKernelGGL((select_kernel<1, 1>), dim3(nblk), dim3(TPB), 0, stream,
                           T, BT, BP, ws, out, boost_out, B);
    } else {
        // generic fallback (R12 semantics)
        hipLaunchKernelGGL(init_ws_kernel, dim3(1), dim3(1), 0, stream, ws);
        hipLaunchKernelGGL((gmax_kernel<0>), dim3(2048), dim3(256), 0, stream,
                           T, ws, n4);
        hipLaunchKernelGGL((select_kernel<0, 0>), dim3(nblk), dim3(TPB), 0, stream,
                           T, BT, BP, ws, out, boost_out, B);
        hipLaunchKernelGGL((select_kernel<1, 0>), dim3(nblk), dim3(TPB), 0, stream,
                           T, BT, BP, ws, out, boost_out, B);
    }
}